// Round 6
// baseline (127.071 us; speedup 1.0000x reference)
//
#include <hip/hip_runtime.h>

// Problem constants (from reference setup_inputs)
#define BB 4096   // batch
#define SS 256    // sequence length
#define FF 64     // features
#define GG 9      // 3*U gate width

#define NEG_LOG2E -1.4426950408889634f
#define TWO_LOG2E  2.8853900817779268f

typedef float f2 __attribute__((ext_vector_type(2)));

#if __has_builtin(__builtin_amdgcn_exp2f)
__device__ __forceinline__ float fast_exp2(float x) { return __builtin_amdgcn_exp2f(x); }
#else
__device__ __forceinline__ float fast_exp2(float x) { return exp2f(x); }
#endif
#if __has_builtin(__builtin_amdgcn_rcpf)
__device__ __forceinline__ float fast_rcp(float x) { return __builtin_amdgcn_rcpf(x); }
#else
__device__ __forceinline__ float fast_rcp(float x) { return 1.0f / x; }
#endif

// Quad-lane DPP helper (verified absmax-0 in R3-R5).
template <int CTRL>
__device__ __forceinline__ float dpp_quad(float v) {
  return __int_as_float(
      __builtin_amdgcn_mov_dpp(__float_as_int(v), CTRL, 0xF, 0xF, true));
}

// -----------------------------------------------------------------------------
// Fully fused GRU, software-pipelined. 256 blocks x 1 wave (one per CU),
// 16 chains/block, 4 lanes/chain with 4-way feature split (R5 structure).
// New in R6: (a) depth-8 register ring (32 load instrs = 32KB/CU in flight,
// Little's-law-saturating); (b) step split into proj (h-independent: 80 pk-FMA
// + quad butterfly) and gate (serial h chain); the group-of-8 body staggers
// gate(p[i]) between proj(R[i+2]) so every serial gate chain and every
// s_waitcnt hides under ~230cy of independent FMA issue.
// -----------------------------------------------------------------------------
__global__ __launch_bounds__(64, 1) void fused_gru_kernel(
    const float* __restrict__ x,           // [B,S,F]
    const float* __restrict__ kernel_w,    // [F,9]
    const float* __restrict__ rec_kernel,  // [3,9]
    const float* __restrict__ bias,        // [2,9]
    const float* __restrict__ dense_w,     // [3,10]
    const float* __restrict__ dense_b,     // [10]
    float* __restrict__ out)               // [B,10]
{
  const int lane = threadIdx.x;        // 0..63
  const int u    = lane & 3;           // quad slot (feature sub-slice / unit)
  const int uc   = (u < 3) ? u : 2;    // lane 3: clamp unit role (benign)
  const int c    = blockIdx.x * 16 + (lane >> 2);  // chain (batch) id

  // ---- input-projection weights for this lane's 16 features (pre-scaled)
  f2 w01[16], w23[16], w45[16], w67[16];
  float w8[16];
#pragma unroll
  for (int j = 0; j < 4; ++j)
#pragma unroll
    for (int e = 0; e < 4; ++e) {
      const int fi = j * 16 + u * 4 + e;   // feature index
      const int sl = j * 4 + e;            // register slot
      const float* kw = kernel_w + fi * GG;
      w01[sl] = (f2){kw[0] * NEG_LOG2E, kw[1] * NEG_LOG2E};
      w23[sl] = (f2){kw[2] * NEG_LOG2E, kw[3] * NEG_LOG2E};
      w45[sl] = (f2){kw[4] * NEG_LOG2E, kw[5] * NEG_LOG2E};
      w67[sl] = (f2){kw[6] * TWO_LOG2E, kw[7] * TWO_LOG2E};
      w8[sl]  = kw[8] * TWO_LOG2E;
    }

  // input bias, pre-scaled AND quartered (quad reduce restores exactly 1x).
  const f2 b01q = {bias[0] * NEG_LOG2E * 0.25f, bias[1] * NEG_LOG2E * 0.25f};
  const f2 b23q = {bias[2] * NEG_LOG2E * 0.25f, bias[3] * NEG_LOG2E * 0.25f};
  const f2 b45q = {bias[4] * NEG_LOG2E * 0.25f, bias[5] * NEG_LOG2E * 0.25f};
  const f2 b67q = {bias[6] * TWO_LOG2E * 0.25f, bias[7] * TWO_LOG2E * 0.25f};
  const float b8q = bias[8] * TWO_LOG2E * 0.25f;

  // recurrent weights/bias for this lane's unit (pre-scaled)
  float wz[3], wr[3], wh[3];
#pragma unroll
  for (int hh = 0; hh < 3; ++hh) {
    wz[hh] = rec_kernel[hh * GG + uc]     * NEG_LOG2E;
    wr[hh] = rec_kernel[hh * GG + 3 + uc] * NEG_LOG2E;
    wh[hh] = rec_kernel[hh * GG + 6 + uc] * TWO_LOG2E;
  }
  const float rbz = bias[GG + uc]     * NEG_LOG2E;
  const float rbr = bias[GG + 3 + uc] * NEG_LOG2E;
  const float rbh = bias[GG + 6 + uc] * TWO_LOG2E;

  float h0 = 0.0f, h1 = 0.0f, h2 = 0.0f, hprev = 0.0f;

  // per-lane x pointer: row (c, s) has 16 float4s; this lane reads col j*4+u.
  const float4* pc = reinterpret_cast<const float4*>(x) + (size_t)c * SS * 16 + u;

  // depth-8 register ring, named buffers, static indexing only
  float4 R0[4], R1[4], R2[4], R3[4], R4[4], R5[4], R6[4], R7[4];
  auto loads = [&](float4 (&Xs)[4], int s) {
#pragma unroll
    for (int j = 0; j < 4; ++j) Xs[j] = pc[(size_t)s * 16 + j * 4];
  };

  // h-independent phase: projection FMAs + quad butterfly + bias fold
  auto proj = [&](const float4 (&Xs)[4], float& oaz, float& oar, float& osh) {
    f2 a01 = b01q, a23 = b23q, a45 = b45q, a67 = b67q;
    float a8 = b8q;
#pragma unroll
    for (int j = 0; j < 4; ++j) {
      const float4 v = Xs[j];
      const int sl = j * 4;
      a01 = v.x * w01[sl+0] + a01; a23 = v.x * w23[sl+0] + a23;
      a45 = v.x * w45[sl+0] + a45; a67 = v.x * w67[sl+0] + a67;
      a8 = fmaf(v.x, w8[sl+0], a8);
      a01 = v.y * w01[sl+1] + a01; a23 = v.y * w23[sl+1] + a23;
      a45 = v.y * w45[sl+1] + a45; a67 = v.y * w67[sl+1] + a67;
      a8 = fmaf(v.y, w8[sl+1], a8);
      a01 = v.z * w01[sl+2] + a01; a23 = v.z * w23[sl+2] + a23;
      a45 = v.z * w45[sl+2] + a45; a67 = v.z * w67[sl+2] + a67;
      a8 = fmaf(v.z, w8[sl+2], a8);
      a01 = v.w * w01[sl+3] + a01; a23 = v.w * w23[sl+3] + a23;
      a45 = v.w * w45[sl+3] + a45; a67 = v.w * w67[sl+3] + a67;
      a8 = fmaf(v.w, w8[sl+3], a8);
    }
    float s0 = a01.x, s1 = a01.y, s2 = a23.x, s3 = a23.y, s4 = a45.x,
          s5 = a45.y, s6 = a67.x, s7 = a67.y, s8 = a8;
    s0 += dpp_quad<0xB1>(s0); s1 += dpp_quad<0xB1>(s1); s2 += dpp_quad<0xB1>(s2);
    s3 += dpp_quad<0xB1>(s3); s4 += dpp_quad<0xB1>(s4); s5 += dpp_quad<0xB1>(s5);
    s6 += dpp_quad<0xB1>(s6); s7 += dpp_quad<0xB1>(s7); s8 += dpp_quad<0xB1>(s8);
    s0 += dpp_quad<0x4E>(s0); s1 += dpp_quad<0x4E>(s1); s2 += dpp_quad<0x4E>(s2);
    s3 += dpp_quad<0x4E>(s3); s4 += dpp_quad<0x4E>(s4); s5 += dpp_quad<0x4E>(s5);
    s6 += dpp_quad<0x4E>(s6); s7 += dpp_quad<0x4E>(s7); s8 += dpp_quad<0x4E>(s8);
    const float sz = (u == 0) ? s0 : ((u == 1) ? s1 : s2);
    const float sr = (u == 0) ? s3 : ((u == 1) ? s4 : s5);
    const float sh = (u == 0) ? s6 : ((u == 1) ? s7 : s8);
    oaz = sz + rbz;  // fold recurrent bias off the h critical path
    oar = sr + rbr;
    osh = sh;
  };

  // serial phase: the h-dependent gate chain
  auto gate = [&](float az, float ar, float sh) {
    const float iz = fmaf(h2, wz[2], fmaf(h1, wz[1], fmaf(h0, wz[0], az)));
    const float ir = fmaf(h2, wr[2], fmaf(h1, wr[1], fmaf(h0, wr[0], ar)));
    const float ih = fmaf(h2, wh[2], fmaf(h1, wh[1], fmaf(h0, wh[0], rbh)));
    const float z = fast_rcp(1.0f + fast_exp2(iz));
    const float r = fast_rcp(1.0f + fast_exp2(ir));
    const float t = fmaf(-2.0f, fast_rcp(1.0f + fast_exp2(fmaf(r, ih, sh))), 1.0f);
    const float hn = fmaf(z, hprev - t, t);
    hprev = hn;
    h0 = dpp_quad<0x00>(hn);
    h1 = dpp_quad<0x55>(hn);
    h2 = dpp_quad<0xAA>(hn);
  };

  loads(R0, 0); loads(R1, 1); loads(R2, 2); loads(R3, 3);
  loads(R4, 4); loads(R5, 5); loads(R6, 6); loads(R7, 7);

  float az0, ar0, sh0, az1, ar1, sh1, az2, ar2, sh2, az3, ar3, sh3;
  float az4, ar4, sh4, az5, ar5, sh5, az6, ar6, sh6, az7, ar7, sh7;

  for (int sg = 0; sg < SS; sg += 8) {
    const int nb = sg + 8;
    // staggered: gate(p[i]) issued between proj(R[i+2]) streams
    proj(R0, az0, ar0, sh0); loads(R0, nb + 0 < SS ? nb + 0 : sg);
    proj(R1, az1, ar1, sh1); loads(R1, nb + 1 < SS ? nb + 1 : sg);
    gate(az0, ar0, sh0);
    proj(R2, az2, ar2, sh2); loads(R2, nb + 2 < SS ? nb + 2 : sg);
    gate(az1, ar1, sh1);
    proj(R3, az3, ar3, sh3); loads(R3, nb + 3 < SS ? nb + 3 : sg);
    gate(az2, ar2, sh2);
    proj(R4, az4, ar4, sh4); loads(R4, nb + 4 < SS ? nb + 4 : sg);
    gate(az3, ar3, sh3);
    proj(R5, az5, ar5, sh5); loads(R5, nb + 5 < SS ? nb + 5 : sg);
    gate(az4, ar4, sh4);
    proj(R6, az6, ar6, sh6); loads(R6, nb + 6 < SS ? nb + 6 : sg);
    gate(az5, ar5, sh5);
    proj(R7, az7, ar7, sh7); loads(R7, nb + 7 < SS ? nb + 7 : sg);
    gate(az6, ar6, sh6);
    gate(az7, ar7, sh7);
  }

  // Dense (3 -> 10) + softmax; h0..h2 broadcast so all quad lanes agree.
  float lg[10];
#pragma unroll
  for (int j = 0; j < 10; ++j)
    lg[j] = dense_b[j] + h0 * dense_w[j] + h1 * dense_w[10 + j] + h2 * dense_w[20 + j];
  float m = lg[0];
#pragma unroll
  for (int j = 1; j < 10; ++j) m = fmaxf(m, lg[j]);
  float e[10];
  float ssum = 0.0f;
#pragma unroll
  for (int j = 0; j < 10; ++j) {
    e[j] = fast_exp2(1.4426950408889634f * (lg[j] - m));
    ssum += e[j];
  }
  const float inv = fast_rcp(ssum);
#pragma unroll
  for (int j = u; j < 10; j += 4) out[(size_t)c * 10 + j] = e[j] * inv;
}

extern "C" void kernel_launch(void* const* d_in, const int* in_sizes, int n_in,
                              void* d_out, int out_size, void* d_ws, size_t ws_size,
                              hipStream_t stream) {
  const float* x      = (const float*)d_in[0];  // [4096,256,64]
  const float* kern   = (const float*)d_in[1];  // [64,9]
  const float* rkern  = (const float*)d_in[2];  // [3,9]
  const float* bias   = (const float*)d_in[3];  // [2,9]
  const float* dw     = (const float*)d_in[4];  // [3,10]
  const float* db     = (const float*)d_in[5];  // [10]
  float* out = (float*)d_out;

  fused_gru_kernel<<<BB / 16, 64, 0, stream>>>(x, kern, rkern, bias, dw, db, out);
}